// Round 1
// baseline (2489.540 us; speedup 1.0000x reference)
//
#include <hip/hip_runtime.h>

// ---------------------------------------------------------------------------
// TokenRoutedBlock: B=2,T=2048,D=2048,H=16,HD=128,K=4,FF=2048, layer-routed
// mixed linears (4-basis) + causal attention + silu-FFN, bf16 MFMA compute.
// ---------------------------------------------------------------------------

typedef __attribute__((ext_vector_type(8))) short short8;   // 8 bf16
typedef __attribute__((ext_vector_type(4))) float f32x4;
typedef __attribute__((ext_vector_type(4))) unsigned uint4_t;

#define BT 4096
#define DD 2048
#define KD 8192          // K*D contraction for mixed linear
#define NH 16
#define HD_ 128
#define RSCALE 0.02209708691207961f      // 1/sqrt(2048)
#define ASCALE 0.08838834764831845f      // 1/sqrt(128)

__device__ inline float bf2f(short s) {
  return __uint_as_float(((unsigned)(unsigned short)s) << 16);
}
__device__ inline short f2bf(float f) {   // RNE
  unsigned u = __float_as_uint(f);
  u += 0x7FFFu + ((u >> 16) & 1u);
  return (short)(u >> 16);
}
__device__ inline f32x4 zero4() { f32x4 v; v[0]=0.f; v[1]=0.f; v[2]=0.f; v[3]=0.f; return v; }

// ---------------------------------------------------------------------------
// RMSNorm * norm_w * gamma + beta  (fp32 in -> bf16 out). One block per token.
__global__ __launch_bounds__(256)
void rmsnorm_kernel(const float* __restrict__ x, const float* __restrict__ w,
                    const float* __restrict__ gamma, const float* __restrict__ beta,
                    short* __restrict__ out) {
  const int t = blockIdx.x;
  const float* xr = x + (size_t)t * DD;
  const int base = threadIdx.x * 8;
  float4 v0 = *(const float4*)(xr + base);
  float4 v1 = *(const float4*)(xr + base + 4);
  float ss = v0.x*v0.x + v0.y*v0.y + v0.z*v0.z + v0.w*v0.w
           + v1.x*v1.x + v1.y*v1.y + v1.z*v1.z + v1.w*v1.w;
  #pragma unroll
  for (int off = 32; off > 0; off >>= 1) ss += __shfl_xor(ss, off, 64);
  __shared__ float red[4];
  const int lane = threadIdx.x & 63, wv = threadIdx.x >> 6;
  if (lane == 0) red[wv] = ss;
  __syncthreads();
  const float tot = red[0] + red[1] + red[2] + red[3];
  const float inv = rsqrtf(tot * (1.0f / DD) + 1.1920929e-07f);
  float xv[8] = {v0.x,v0.y,v0.z,v0.w,v1.x,v1.y,v1.z,v1.w};
  short8 o;
  #pragma unroll
  for (int j = 0; j < 8; ++j)
    o[j] = f2bf(xv[j] * inv * w[base+j] * gamma[base+j] + beta[base+j]);
  *(short8*)(out + (size_t)t * DD + base) = o;
}

// ---------------------------------------------------------------------------
// Routing: logits = (x . route_l)/sqrt(2048) + bias_l ; alpha = softmax_k.
// One wave per token.
__global__ __launch_bounds__(64)
void route_kernel(const short* __restrict__ in,      // (BT, 2048) bf16
                  const float* __restrict__ routeB,  // (L, 4, 2048)
                  const float* __restrict__ biasB,   // (L, 4)
                  const int* __restrict__ li_ptr,
                  float* __restrict__ alpha,         // (BT, 4)
                  float* __restrict__ aout)          // optional copy (a_qkv)
{
  const int t = blockIdx.x;
  const int lane = threadIdx.x;
  const int li = *li_ptr;
  const float* R = routeB + (size_t)li * 4 * DD;
  const float* bias = biasB + li * 4;
  const short* xr = in + (size_t)t * DD;
  float acc0 = 0.f, acc1 = 0.f, acc2 = 0.f, acc3 = 0.f;
  for (int i = lane; i < DD; i += 64) {
    float v = bf2f(xr[i]);
    acc0 += v * R[i];
    acc1 += v * R[DD + i];
    acc2 += v * R[2*DD + i];
    acc3 += v * R[3*DD + i];
  }
  #pragma unroll
  for (int off = 32; off > 0; off >>= 1) {
    acc0 += __shfl_xor(acc0, off, 64);
    acc1 += __shfl_xor(acc1, off, 64);
    acc2 += __shfl_xor(acc2, off, 64);
    acc3 += __shfl_xor(acc3, off, 64);
  }
  if (lane == 0) {
    float lg[4] = {acc0 * RSCALE + bias[0], acc1 * RSCALE + bias[1],
                   acc2 * RSCALE + bias[2], acc3 * RSCALE + bias[3]};
    float mx = fmaxf(fmaxf(lg[0], lg[1]), fmaxf(lg[2], lg[3]));
    float se = 0.f;
    #pragma unroll
    for (int k = 0; k < 4; ++k) { lg[k] = __expf(lg[k] - mx); se += lg[k]; }
    const float rinv = 1.0f / se;
    #pragma unroll
    for (int k = 0; k < 4; ++k) {
      float a = lg[k] * rinv;
      alpha[(size_t)t*4 + k] = a;
      if (aout) aout[(size_t)t*4 + k] = a;
    }
  }
}

// ---------------------------------------------------------------------------
// Expand: Aexp[t, k*2048+d] = alpha[t,k] * in[t,d]   (bf16)
__global__ __launch_bounds__(256)
void expand_kernel(const short* __restrict__ in, const float* __restrict__ alpha,
                   short* __restrict__ out)   // (BT, 8192)
{
  const int t = blockIdx.x;
  const short* hr = in + (size_t)t * DD;
  const float a0 = alpha[(size_t)t*4], a1 = alpha[(size_t)t*4+1],
              a2 = alpha[(size_t)t*4+2], a3 = alpha[(size_t)t*4+3];
  const float av[4] = {a0, a1, a2, a3};
  #pragma unroll
  for (int c = 0; c < 4; ++c) {
    int ci = threadIdx.x + 256 * c;       // chunk of 8 elems, 1024 chunks
    int kk = ci * 8;
    int kidx = kk >> 11;
    int d = kk & 2047;
    short8 v = *(const short8*)(hr + d);
    float s = av[kidx];
    short8 o;
    #pragma unroll
    for (int j = 0; j < 8; ++j) o[j] = f2bf(bf2f(v[j]) * s);
    *(short8*)(out + (size_t)t * KD + kk) = o;
  }
}

// ---------------------------------------------------------------------------
// GEMM: C(4096 x N) = Aexp(4096 x 8192) * Bw^T where Bw is (4, N, 2048) fp32
// (bases). 128x128 tile, 4 waves (2x2), 16x16x32 bf16 MFMA, BK=64.
// mode 0: bf16 out (stride N)
// mode 2: fp32 out = xres + acc            (N==2048)
// mode 3: fp32 out = xres + (xattn + acc - xres)*iter_s   (N==2048)
__global__ __launch_bounds__(256, 2)
void gemm_mixed(const short* __restrict__ Aexp,
                const float* __restrict__ Bw,
                const int N, const int mode,
                const float* __restrict__ xres,
                const float* __restrict__ xattn,
                const float* __restrict__ iter_s,
                void* __restrict__ outp)
{
  __shared__ __align__(16) short As[128][72];
  __shared__ __align__(16) short Bs[128][72];
  const int tid = threadIdx.x;
  const int lane = tid & 63, wave = tid >> 6;
  const int lr = lane & 15, lg = lane >> 4;
  const int wm = (wave & 1) * 64, wn = (wave >> 1) * 64;
  const int m0 = blockIdx.y * 128, n0 = blockIdx.x * 128;

  f32x4 acc[4][4];
  #pragma unroll
  for (int i = 0; i < 4; ++i)
    #pragma unroll
    for (int j = 0; j < 4; ++j) acc[i][j] = zero4();

  for (int kt = 0; kt < 128; ++kt) {      // 8192 / 64
    const int kk0 = kt * 64;
    const int kidx = kk0 >> 11;
    const int dbase = kk0 & 2047;
    // stage A (pure bf16 copy): 1024 chunks of 8 elems
    #pragma unroll
    for (int c = 0; c < 4; ++c) {
      int ci = tid + 256 * c;
      int row = ci >> 3, col8 = ci & 7;
      short8 v = *(const short8*)(Aexp + (size_t)(m0 + row) * KD + kk0 + col8*8);
      *(short8*)&As[row][col8*8] = v;
    }
    // stage B (fp32 -> bf16 truncate via v_perm)
    #pragma unroll
    for (int c = 0; c < 4; ++c) {
      int ci = tid + 256 * c;
      int row = ci >> 3, col8 = ci & 7;
      const float* bp = Bw + ((size_t)kidx * N + (n0 + row)) * DD + dbase + col8*8;
      float4 u0 = *(const float4*)bp;
      float4 u1 = *(const float4*)(bp + 4);
      uint4_t pk;
      pk[0] = __builtin_amdgcn_perm(__float_as_uint(u0.y), __float_as_uint(u0.x), 0x07060302);
      pk[1] = __builtin_amdgcn_perm(__float_as_uint(u0.w), __float_as_uint(u0.z), 0x07060302);
      pk[2] = __builtin_amdgcn_perm(__float_as_uint(u1.y), __float_as_uint(u1.x), 0x07060302);
      pk[3] = __builtin_amdgcn_perm(__float_as_uint(u1.w), __float_as_uint(u1.z), 0x07060302);
      *(uint4_t*)&Bs[row][col8*8] = pk;
    }
    __syncthreads();
    #pragma unroll
    for (int s = 0; s < 2; ++s) {
      short8 af[4], bfr[4];
      #pragma unroll
      for (int i = 0; i < 4; ++i) af[i]  = *(const short8*)&As[wm + i*16 + lr][s*32 + lg*8];
      #pragma unroll
      for (int j = 0; j < 4; ++j) bfr[j] = *(const short8*)&Bs[wn + j*16 + lr][s*32 + lg*8];
      #pragma unroll
      for (int i = 0; i < 4; ++i)
        #pragma unroll
        for (int j = 0; j < 4; ++j)
          acc[i][j] = __builtin_amdgcn_mfma_f32_16x16x32_bf16(af[i], bfr[j], acc[i][j], 0, 0, 0);
    }
    __syncthreads();
  }
  // epilogue; C layout: col = lane&15, row = (lane>>4)*4 + reg
  const float is = (mode == 3) ? *iter_s : 0.f;
  #pragma unroll
  for (int i = 0; i < 4; ++i) {
    #pragma unroll
    for (int r = 0; r < 4; ++r) {
      const int m = m0 + wm + i*16 + lg*4 + r;
      #pragma unroll
      for (int j = 0; j < 4; ++j) {
        const int n = n0 + wn + j*16 + lr;
        const float v = acc[i][j][r];
        const size_t idx = (size_t)m * N + n;
        if (mode == 0) {
          ((short*)outp)[idx] = f2bf(v);
        } else if (mode == 2) {
          ((float*)outp)[idx] = xres[idx] + v;
        } else {
          const float xv = xres[idx];
          ((float*)outp)[idx] = xv + (xattn[idx] + v - xv) * is;
        }
      }
    }
  }
}

// ---------------------------------------------------------------------------
// Transpose V out of qkv into (B*H, HD, T) bf16 so attention can stage V^T
// with vector loads.
__global__ __launch_bounds__(256)
void transpose_v_kernel(const short* __restrict__ qkv, short* __restrict__ vt)
{
  __shared__ __align__(16) short tile[64][72];
  const int t0 = blockIdx.x * 64;
  const int hd0 = blockIdx.y * 64;
  const int bh = blockIdx.z;
  const int b = bh >> 4, h = bh & 15;
  const int tid = threadIdx.x;
  #pragma unroll
  for (int c = 0; c < 2; ++c) {
    int ci = tid + 256 * c;
    int tr = ci >> 3, c8 = ci & 7;
    *(short8*)&tile[tr][c8*8] =
      *(const short8*)(qkv + (size_t)(b*2048 + t0 + tr)*6144 + 4096 + h*HD_ + hd0 + c8*8);
  }
  __syncthreads();
  #pragma unroll
  for (int c = 0; c < 2; ++c) {
    int ci = tid + 256 * c;
    int hr = ci >> 3, c8 = ci & 7;
    short8 o;
    #pragma unroll
    for (int j = 0; j < 8; ++j) o[j] = tile[c8*8 + j][hr];
    *(short8*)(vt + (size_t)(bh*HD_ + hd0 + hr)*2048 + t0 + c8*8) = o;
  }
}

// ---------------------------------------------------------------------------
// Flash attention (causal). Block = 4 waves; wave w owns 16 q-rows.
// Tiles of 32 keys; QK^T and PV via 16x16x32 bf16 MFMA; P goes through LDS
// (C-layout -> A-layout).
__global__ __launch_bounds__(256, 2)
void attn_kernel(const short* __restrict__ qkv,   // (4096, 6144) bf16
                 const short* __restrict__ vt,    // (32, 128, 2048) bf16
                 short* __restrict__ attnout)     // (4096, 2048) bf16
{
  __shared__ __align__(16) short Ks[32][136];
  __shared__ __align__(16) short Vt[128][40];
  __shared__ __align__(16) short Ps[4][16][40];
  const int bid = blockIdx.x;
  const int qt = bid & 31, bh = bid >> 5;
  const int b = bh >> 4, h = bh & 15;
  const int q0 = qt * 64;
  const int tid = threadIdx.x, lane = tid & 63, w = tid >> 6;
  const int lr = lane & 15, lg = lane >> 4;
  const int q0w = q0 + w * 16;

  // preload Q fragments: A[m=lr][k = s*32 + lg*8 + j]
  short8 qf[4];
  {
    const size_t qbase = (size_t)(b*2048 + q0w + lr) * 6144 + h * HD_;
    #pragma unroll
    for (int s = 0; s < 4; ++s)
      qf[s] = *(const short8*)(qkv + qbase + s*32 + lg*8);
  }
  float m_run[4], l_run[4];
  f32x4 acc[8];
  #pragma unroll
  for (int r = 0; r < 4; ++r) { m_run[r] = -1e30f; l_run[r] = 0.f; }
  #pragma unroll
  for (int dt = 0; dt < 8; ++dt) acc[dt] = zero4();

  const int ntiles = (q0 + 64) >> 5;
  for (int jt = 0; jt < ntiles; ++jt) {
    const int j0 = jt << 5;
    // stage K tile (32 x 128) and V^T tile (128 x 32)
    #pragma unroll
    for (int c = 0; c < 2; ++c) {
      int ci = tid + 256 * c;
      int key = ci >> 4, hd8 = ci & 15;
      *(short8*)&Ks[key][hd8*8] =
        *(const short8*)(qkv + (size_t)(b*2048 + j0 + key)*6144 + 2048 + h*HD_ + hd8*8);
    }
    #pragma unroll
    for (int c = 0; c < 2; ++c) {
      int ci = tid + 256 * c;
      int hd = ci >> 2, k8 = ci & 3;
      *(short8*)&Vt[hd][k8*8] =
        *(const short8*)(vt + (size_t)(bh*HD_ + hd)*2048 + j0 + k8*8);
    }
    __syncthreads();
    // S = Q K^T  (two 16-key halves)
    f32x4 sc0 = zero4(), sc1 = zero4();
    #pragma unroll
    for (int s = 0; s < 4; ++s) {
      short8 kb0 = *(const short8*)&Ks[lr][s*32 + lg*8];
      short8 kb1 = *(const short8*)&Ks[16 + lr][s*32 + lg*8];
      sc0 = __builtin_amdgcn_mfma_f32_16x16x32_bf16(qf[s], kb0, sc0, 0, 0, 0);
      sc1 = __builtin_amdgcn_mfma_f32_16x16x32_bf16(qf[s], kb1, sc1, 0, 0, 0);
    }
    // online softmax (per row r; columns spread over lr lanes)
    float pv0[4], pv1[4], al[4];
    #pragma unroll
    for (int r = 0; r < 4; ++r) {
      const int q = q0w + lg*4 + r;
      float v0 = sc0[r] * ASCALE; if (j0 + lr > q)      v0 = -1e30f;
      float v1 = sc1[r] * ASCALE; if (j0 + 16 + lr > q) v1 = -1e30f;
      float mx = fmaxf(v0, v1);
      mx = fmaxf(mx, __shfl_xor(mx, 1, 16));
      mx = fmaxf(mx, __shfl_xor(mx, 2, 16));
      mx = fmaxf(mx, __shfl_xor(mx, 4, 16));
      mx = fmaxf(mx, __shfl_xor(mx, 8, 16));
      const float mnew = fmaxf(m_run[r], mx);
      const float a = __expf(m_run[r] - mnew);
      v0 = __expf(v0 - mnew);
      v1 = __expf(v1 - mnew);
      float rs = v0 + v1;
      rs += __shfl_xor(rs, 1, 16);
      rs += __shfl_xor(rs, 2, 16);
      rs += __shfl_xor(rs, 4, 16);
      rs += __shfl_xor(rs, 8, 16);
      l_run[r] = l_run[r] * a + rs;
      m_run[r] = mnew;
      al[r] = a; pv0[r] = v0; pv1[r] = v1;
    }
    #pragma unroll
    for (int dt = 0; dt < 8; ++dt)
      #pragma unroll
      for (int r = 0; r < 4; ++r) acc[dt][r] *= al[r];
    // P: C-layout -> LDS -> A-layout
    #pragma unroll
    for (int r = 0; r < 4; ++r) {
      Ps[w][lg*4 + r][lr]      = f2bf(pv0[r]);
      Ps[w][lg*4 + r][16 + lr] = f2bf(pv1[r]);
    }
    short8 pa = *(const short8*)&Ps[w][lr][lg*8];
    #pragma unroll
    for (int dt = 0; dt < 8; ++dt) {
      short8 vb = *(const short8*)&Vt[dt*16 + lr][lg*8];
      acc[dt] = __builtin_amdgcn_mfma_f32_16x16x32_bf16(pa, vb, acc[dt], 0, 0, 0);
    }
    __syncthreads();
  }
  #pragma unroll
  for (int dt = 0; dt < 8; ++dt) {
    #pragma unroll
    for (int r = 0; r < 4; ++r) {
      const int q = q0w + lg*4 + r;
      attnout[(size_t)(b*2048 + q)*2048 + h*HD_ + dt*16 + lr] = f2bf(acc[dt][r] / l_run[r]);
    }
  }
}

// ---------------------------------------------------------------------------
// ffn_in = silu(gate) * up   (bf16)
__global__ __launch_bounds__(256)
void silu_mul_kernel(const short* __restrict__ g, const short* __restrict__ u,
                     short* __restrict__ out)
{
  const int i = blockIdx.x * 256 + threadIdx.x;   // per short8 chunk
  short8 gv = ((const short8*)g)[i];
  short8 uv = ((const short8*)u)[i];
  short8 o;
  #pragma unroll
  for (int j = 0; j < 8; ++j) {
    float xg = bf2f(gv[j]);
    float s = xg / (1.0f + __expf(-xg));
    o[j] = f2bf(s * bf2f(uv[j]));
  }
  ((short8*)out)[i] = o;
}

// ---------------------------------------------------------------------------
extern "C" void kernel_launch(void* const* d_in, const int* in_sizes, int n_in,
                              void* d_out, int out_size, void* d_ws, size_t ws_size,
                              hipStream_t stream) {
  const float* x          = (const float*)d_in[0];
  const float* gamma      = (const float*)d_in[1];
  const float* beta       = (const float*)d_in[2];
  const float* iter_scale = (const float*)d_in[3];
  const float* qkv_bases  = (const float*)d_in[4];
  const float* o_bases    = (const float*)d_in[5];
  const float* gate_bases = (const float*)d_in[6];
  const float* up_bases   = (const float*)d_in[7];
  const float* down_bases = (const float*)d_in[8];
  const float* route_qkv  = (const float*)d_in[9];
  const float* route_o    = (const float*)d_in[10];
  const float* route_gate = (const float*)d_in[11];
  const float* route_up   = (const float*)d_in[12];
  const float* route_down = (const float*)d_in[13];
  const float* bias_qkv   = (const float*)d_in[14];
  const float* bias_o     = (const float*)d_in[15];
  const float* bias_gate  = (const float*)d_in[16];
  const float* bias_up    = (const float*)d_in[17];
  const float* bias_down  = (const float*)d_in[18];
  const float* norm1_w    = (const float*)d_in[19];
  const float* norm2_w    = (const float*)d_in[20];
  const int*   li         = (const int*)d_in[21];

  float* out0 = (float*)d_out;                  // (B,T,D) fp32
  float* aout = out0 + (size_t)BT * DD;         // a_qkv (B,T,4) fp32

  char* ws = (char*)d_ws;
  short* hbuf    = (short*)(ws + 0);            // 16.78 MB  (h / h2, bf16)
  float* alpha   = (float*)(ws + 16777216);     // 64 KB (+slack)
  short* Aexp    = (short*)(ws + 16973824);     // 67.1 MB  (BT x 8192 bf16)
  short* qkvbuf  = (short*)(ws + 84082688);     // 50.3 MB  (BT x 6144 bf16)
  short* attnout = (short*)(ws + 134414336);    // 16.78 MB
  short* vtbuf   = (short*)(ws + 151191552);    // 16.78 MB ; total 167.97 MB
  // aliases (lifetimes are disjoint):
  float* x_attn  = (float*)(ws + 84082688);     // 33.55 MB over dead qkvbuf
  short* gatebuf = (short*)(ws + 117637120);    // 16.78 MB over dead qkvbuf tail
  short* upbuf   = (short*)(ws + 134414336);    // over dead attnout

  // h = rmsnorm(x, norm1_w)*gamma + beta
  rmsnorm_kernel<<<BT, 256, 0, stream>>>(x, norm1_w, gamma, beta, hbuf);
  // qkv mixed linear (also emits a_qkv output)
  route_kernel<<<BT, 64, 0, stream>>>(hbuf, route_qkv, bias_qkv, li, alpha, aout);
  expand_kernel<<<BT, 256, 0, stream>>>(hbuf, alpha, Aexp);
  gemm_mixed<<<dim3(48, 32), 256, 0, stream>>>(Aexp, qkv_bases, 6144, 0,
                                               nullptr, nullptr, nullptr, qkvbuf);
  // attention
  transpose_v_kernel<<<dim3(32, 2, 32), 256, 0, stream>>>(qkvbuf, vtbuf);
  attn_kernel<<<1024, 256, 0, stream>>>(qkvbuf, vtbuf, attnout);
  // o mixed linear + residual -> x_attn (fp32)
  route_kernel<<<BT, 64, 0, stream>>>(attnout, route_o, bias_o, li, alpha, nullptr);
  expand_kernel<<<BT, 256, 0, stream>>>(attnout, alpha, Aexp);
  gemm_mixed<<<dim3(16, 32), 256, 0, stream>>>(Aexp, o_bases, 2048, 2,
                                               x, nullptr, nullptr, x_attn);
  // h2 = rmsnorm(x_attn, norm2_w)*gamma + beta
  rmsnorm_kernel<<<BT, 256, 0, stream>>>(x_attn, norm2_w, gamma, beta, hbuf);
  // gate
  route_kernel<<<BT, 64, 0, stream>>>(hbuf, route_gate, bias_gate, li, alpha, nullptr);
  expand_kernel<<<BT, 256, 0, stream>>>(hbuf, alpha, Aexp);
  gemm_mixed<<<dim3(16, 32), 256, 0, stream>>>(Aexp, gate_bases, 2048, 0,
                                               nullptr, nullptr, nullptr, gatebuf);
  // up
  route_kernel<<<BT, 64, 0, stream>>>(hbuf, route_up, bias_up, li, alpha, nullptr);
  expand_kernel<<<BT, 256, 0, stream>>>(hbuf, alpha, Aexp);
  gemm_mixed<<<dim3(16, 32), 256, 0, stream>>>(Aexp, up_bases, 2048, 0,
                                               nullptr, nullptr, nullptr, upbuf);
  // ffn_in = silu(gate)*up
  silu_mul_kernel<<<4096, 256, 0, stream>>>(gatebuf, upbuf, gatebuf);
  // down mixed linear + final residual/iter_scale -> out0
  route_kernel<<<BT, 64, 0, stream>>>(gatebuf, route_down, bias_down, li, alpha, nullptr);
  expand_kernel<<<BT, 256, 0, stream>>>(gatebuf, alpha, Aexp);
  gemm_mixed<<<dim3(16, 32), 256, 0, stream>>>(Aexp, down_bases, 2048, 3,
                                               x, x_attn, iter_scale, out0);
}

// Round 2
// 2143.979 us; speedup vs baseline: 1.1612x; 1.1612x over previous
//
#include <hip/hip_runtime.h>

// ---------------------------------------------------------------------------
// TokenRoutedBlock: B=2,T=2048,D=2048,H=16,HD=128,K=4,FF=2048, layer-routed
// mixed linears (4-basis) + causal attention + silu-FFN, bf16 MFMA compute.
// R2: bases pre-converted to bf16; GEMM staging via global_load_lds width=16
// (m97 structure: 2-barrier K-loop, unpadded 128x64 LDS tiles).
// ---------------------------------------------------------------------------

typedef __attribute__((ext_vector_type(8))) short short8;   // 8 bf16
typedef __attribute__((ext_vector_type(4))) float f32x4;
typedef __attribute__((ext_vector_type(4))) unsigned uint4_t;

#define BT 4096
#define DD 2048
#define KD 8192          // K*D contraction for mixed linear
#define NH 16
#define HD_ 128
#define RSCALE 0.02209708691207961f      // 1/sqrt(2048)
#define ASCALE 0.08838834764831845f      // 1/sqrt(128)

__device__ inline float bf2f(short s) {
  return __uint_as_float(((unsigned)(unsigned short)s) << 16);
}
__device__ inline short f2bf(float f) {   // RNE
  unsigned u = __float_as_uint(f);
  u += 0x7FFFu + ((u >> 16) & 1u);
  return (short)(u >> 16);
}
__device__ inline f32x4 zero4() { f32x4 v; v[0]=0.f; v[1]=0.f; v[2]=0.f; v[3]=0.f; return v; }

// async 16B global -> LDS (DMA, no VGPR round-trip). LDS dest must be
// wave-uniform base + lane*16 (linear layout, no padding).
__device__ inline void async_copy16(const void* g, void* l) {
  __builtin_amdgcn_global_load_lds(
      (const __attribute__((address_space(1))) unsigned*)g,
      (__attribute__((address_space(3))) unsigned*)l, 16, 0, 0);
}

// ---------------------------------------------------------------------------
// fp32 -> bf16 (truncate) bulk conversion, 8 elems/thread.
__global__ __launch_bounds__(256)
void cvt_bf16_kernel(const float* __restrict__ in, short* __restrict__ out,
                     const int nchunk) {
  const int i = blockIdx.x * 256 + threadIdx.x;
  if (i >= nchunk) return;
  const float* p = in + (size_t)i * 8;
  float4 u0 = *(const float4*)p;
  float4 u1 = *(const float4*)(p + 4);
  uint4_t pk;
  pk[0] = __builtin_amdgcn_perm(__float_as_uint(u0.y), __float_as_uint(u0.x), 0x07060302);
  pk[1] = __builtin_amdgcn_perm(__float_as_uint(u0.w), __float_as_uint(u0.z), 0x07060302);
  pk[2] = __builtin_amdgcn_perm(__float_as_uint(u1.y), __float_as_uint(u1.x), 0x07060302);
  pk[3] = __builtin_amdgcn_perm(__float_as_uint(u1.w), __float_as_uint(u1.z), 0x07060302);
  *(uint4_t*)(out + (size_t)i * 8) = pk;
}

// ---------------------------------------------------------------------------
// RMSNorm * norm_w * gamma + beta  (fp32 in -> bf16 out). One block per token.
__global__ __launch_bounds__(256)
void rmsnorm_kernel(const float* __restrict__ x, const float* __restrict__ w,
                    const float* __restrict__ gamma, const float* __restrict__ beta,
                    short* __restrict__ out) {
  const int t = blockIdx.x;
  const float* xr = x + (size_t)t * DD;
  const int base = threadIdx.x * 8;
  float4 v0 = *(const float4*)(xr + base);
  float4 v1 = *(const float4*)(xr + base + 4);
  float ss = v0.x*v0.x + v0.y*v0.y + v0.z*v0.z + v0.w*v0.w
           + v1.x*v1.x + v1.y*v1.y + v1.z*v1.z + v1.w*v1.w;
  #pragma unroll
  for (int off = 32; off > 0; off >>= 1) ss += __shfl_xor(ss, off, 64);
  __shared__ float red[4];
  const int lane = threadIdx.x & 63, wv = threadIdx.x >> 6;
  if (lane == 0) red[wv] = ss;
  __syncthreads();
  const float tot = red[0] + red[1] + red[2] + red[3];
  const float inv = rsqrtf(tot * (1.0f / DD) + 1.1920929e-07f);
  float xv[8] = {v0.x,v0.y,v0.z,v0.w,v1.x,v1.y,v1.z,v1.w};
  short8 o;
  #pragma unroll
  for (int j = 0; j < 8; ++j)
    o[j] = f2bf(xv[j] * inv * w[base+j] * gamma[base+j] + beta[base+j]);
  *(short8*)(out + (size_t)t * DD + base) = o;
}

// ---------------------------------------------------------------------------
// Routing: logits = (x . route_l)/sqrt(2048) + bias_l ; alpha = softmax_k.
// One wave per token.
__global__ __launch_bounds__(64)
void route_kernel(const short* __restrict__ in,      // (BT, 2048) bf16
                  const float* __restrict__ routeB,  // (L, 4, 2048)
                  const float* __restrict__ biasB,   // (L, 4)
                  const int* __restrict__ li_ptr,
                  float* __restrict__ alpha,         // (BT, 4)
                  float* __restrict__ aout)          // optional copy (a_qkv)
{
  const int t = blockIdx.x;
  const int lane = threadIdx.x;
  const int li = *li_ptr;
  const float* R = routeB + (size_t)li * 4 * DD;
  const float* bias = biasB + li * 4;
  const short* xr = in + (size_t)t * DD;
  float acc0 = 0.f, acc1 = 0.f, acc2 = 0.f, acc3 = 0.f;
  for (int i = lane; i < DD; i += 64) {
    float v = bf2f(xr[i]);
    acc0 += v * R[i];
    acc1 += v * R[DD + i];
    acc2 += v * R[2*DD + i];
    acc3 += v * R[3*DD + i];
  }
  #pragma unroll
  for (int off = 32; off > 0; off >>= 1) {
    acc0 += __shfl_xor(acc0, off, 64);
    acc1 += __shfl_xor(acc1, off, 64);
    acc2 += __shfl_xor(acc2, off, 64);
    acc3 += __shfl_xor(acc3, off, 64);
  }
  if (lane == 0) {
    float lg[4] = {acc0 * RSCALE + bias[0], acc1 * RSCALE + bias[1],
                   acc2 * RSCALE + bias[2], acc3 * RSCALE + bias[3]};
    float mx = fmaxf(fmaxf(lg[0], lg[1]), fmaxf(lg[2], lg[3]));
    float se = 0.f;
    #pragma unroll
    for (int k = 0; k < 4; ++k) { lg[k] = __expf(lg[k] - mx); se += lg[k]; }
    const float rinv = 1.0f / se;
    #pragma unroll
    for (int k = 0; k < 4; ++k) {
      float a = lg[k] * rinv;
      alpha[(size_t)t*4 + k] = a;
      if (aout) aout[(size_t)t*4 + k] = a;
    }
  }
}

// ---------------------------------------------------------------------------
// Expand: Aexp[t, k*2048+d] = alpha[t,k] * in[t,d]   (bf16)
__global__ __launch_bounds__(256)
void expand_kernel(const short* __restrict__ in, const float* __restrict__ alpha,
                   short* __restrict__ out)   // (BT, 8192)
{
  const int t = blockIdx.x;
  const short* hr = in + (size_t)t * DD;
  const float a0 = alpha[(size_t)t*4], a1 = alpha[(size_t)t*4+1],
              a2 = alpha[(size_t)t*4+2], a3 = alpha[(size_t)t*4+3];
  const float av[4] = {a0, a1, a2, a3};
  #pragma unroll
  for (int c = 0; c < 4; ++c) {
    int ci = threadIdx.x + 256 * c;       // chunk of 8 elems, 1024 chunks
    int kk = ci * 8;
    int kidx = kk >> 11;
    int d = kk & 2047;
    short8 v = *(const short8*)(hr + d);
    float s = av[kidx];
    short8 o;
    #pragma unroll
    for (int j = 0; j < 8; ++j) o[j] = f2bf(bf2f(v[j]) * s);
    *(short8*)(out + (size_t)t * KD + kk) = o;
  }
}

// ---------------------------------------------------------------------------
// GEMM: C(4096 x N) = Aexp(4096 x 8192) * Bwb^T where Bwb is (4, N, 2048) bf16
// (pre-converted bases). 128x128 tile, 4 waves (2x2), 16x16x32 bf16 MFMA,
// BK=64, global_load_lds width-16 staging (m97 structure).
// mode 0: bf16 out (stride N)
// mode 2: fp32 out = xres + acc            (N==2048)
// mode 3: fp32 out = xres + (xattn + acc - xres)*iter_s   (N==2048)
__global__ __launch_bounds__(256)
void gemm_mixed(const short* __restrict__ Aexp,
                const short* __restrict__ Bwb,
                const int N, const int mode,
                const float* __restrict__ xres,
                const float* __restrict__ xattn,
                const float* __restrict__ iter_s,
                void* __restrict__ outp)
{
  __shared__ __align__(16) short As[128*64];   // 16 KB, linear (no pad: DMA dest)
  __shared__ __align__(16) short Bs[128*64];   // 16 KB
  const int tid = threadIdx.x;
  const int lane = tid & 63, wave = tid >> 6;
  const int lr = lane & 15, lg = lane >> 4;
  const int wm = (wave & 1) * 64, wn = (wave >> 1) * 64;
  const int m0 = blockIdx.y * 128, n0 = blockIdx.x * 128;

  f32x4 acc[4][4];
  #pragma unroll
  for (int i = 0; i < 4; ++i)
    #pragma unroll
    for (int j = 0; j < 4; ++j) acc[i][j] = zero4();

  // staging geometry: chunk i = c*256+tid covers (row=i>>3, 8 bf16 at col (i&7)*8)
  const int srow = tid >> 3, sc8 = tid & 7;
  const short* Ab = Aexp + (size_t)(m0 + srow) * KD + sc8 * 8;
  const short* Bb = Bwb + (size_t)(n0 + srow) * DD + sc8 * 8;

  for (int kt = 0; kt < 128; ++kt) {      // 8192 / 64
    const int kk0 = kt << 6;
    const int kidx = kk0 >> 11;          // which basis
    const int dbase = kk0 & 2047;        // offset within D
    #pragma unroll
    for (int c = 0; c < 4; ++c) {
      const int i = tid + 256 * c;       // c advances row by 32
      async_copy16(Ab + (size_t)(c * 32) * KD + kk0, As + i * 8);
      async_copy16(Bb + ((size_t)kidx * N + c * 32) * DD + dbase, Bs + i * 8);
    }
    __syncthreads();                     // compiler drains vmcnt before barrier
    #pragma unroll
    for (int s = 0; s < 2; ++s) {
      short8 af[4], bfr[4];
      #pragma unroll
      for (int i = 0; i < 4; ++i) af[i]  = *(const short8*)(As + (wm + i*16 + lr)*64 + s*32 + lg*8);
      #pragma unroll
      for (int j = 0; j < 4; ++j) bfr[j] = *(const short8*)(Bs + (wn + j*16 + lr)*64 + s*32 + lg*8);
      #pragma unroll
      for (int i = 0; i < 4; ++i)
        #pragma unroll
        for (int j = 0; j < 4; ++j)
          acc[i][j] = __builtin_amdgcn_mfma_f32_16x16x32_bf16(af[i], bfr[j], acc[i][j], 0, 0, 0);
    }
    __syncthreads();
  }
  // epilogue; C layout: col = lane&15, row = (lane>>4)*4 + reg
  const float is = (mode == 3) ? *iter_s : 0.f;
  #pragma unroll
  for (int i = 0; i < 4; ++i) {
    #pragma unroll
    for (int r = 0; r < 4; ++r) {
      const int m = m0 + wm + i*16 + lg*4 + r;
      #pragma unroll
      for (int j = 0; j < 4; ++j) {
        const int n = n0 + wn + j*16 + lr;
        const float v = acc[i][j][r];
        const size_t idx = (size_t)m * N + n;
        if (mode == 0) {
          ((short*)outp)[idx] = f2bf(v);
        } else if (mode == 2) {
          ((float*)outp)[idx] = xres[idx] + v;
        } else {
          const float xv = xres[idx];
          ((float*)outp)[idx] = xv + (xattn[idx] + v - xv) * is;
        }
      }
    }
  }
}

// ---------------------------------------------------------------------------
// Transpose V out of qkv into (B*H, HD, T) bf16 so attention can stage V^T
// with vector loads.
__global__ __launch_bounds__(256)
void transpose_v_kernel(const short* __restrict__ qkv, short* __restrict__ vt)
{
  __shared__ __align__(16) short tile[64][72];
  const int t0 = blockIdx.x * 64;
  const int hd0 = blockIdx.y * 64;
  const int bh = blockIdx.z;
  const int b = bh >> 4, h = bh & 15;
  const int tid = threadIdx.x;
  #pragma unroll
  for (int c = 0; c < 2; ++c) {
    int ci = tid + 256 * c;
    int tr = ci >> 3, c8 = ci & 7;
    *(short8*)&tile[tr][c8*8] =
      *(const short8*)(qkv + (size_t)(b*2048 + t0 + tr)*6144 + 4096 + h*HD_ + hd0 + c8*8);
  }
  __syncthreads();
  #pragma unroll
  for (int c = 0; c < 2; ++c) {
    int ci = tid + 256 * c;
    int hr = ci >> 3, c8 = ci & 7;
    short8 o;
    #pragma unroll
    for (int j = 0; j < 8; ++j) o[j] = tile[c8*8 + j][hr];
    *(short8*)(vt + (size_t)(bh*HD_ + hd0 + hr)*2048 + t0 + c8*8) = o;
  }
}

// ---------------------------------------------------------------------------
// Flash attention (causal). Block = 4 waves; wave w owns 16 q-rows.
// Tiles of 32 keys; QK^T and PV via 16x16x32 bf16 MFMA; P goes through LDS
// (C-layout -> A-layout).
__global__ __launch_bounds__(256, 2)
void attn_kernel(const short* __restrict__ qkv,   // (4096, 6144) bf16
                 const short* __restrict__ vt,    // (32, 128, 2048) bf16
                 short* __restrict__ attnout)     // (4096, 2048) bf16
{
  __shared__ __align__(16) short Ks[32][136];
  __shared__ __align__(16) short Vt[128][40];
  __shared__ __align__(16) short Ps[4][16][40];
  const int bid = blockIdx.x;
  const int qt = bid & 31, bh = bid >> 5;
  const int b = bh >> 4, h = bh & 15;
  const int q0 = qt * 64;
  const int tid = threadIdx.x, lane = tid & 63, w = tid >> 6;
  const int lr = lane & 15, lg = lane >> 4;
  const int q0w = q0 + w * 16;

  // preload Q fragments: A[m=lr][k = s*32 + lg*8 + j]
  short8 qf[4];
  {
    const size_t qbase = (size_t)(b*2048 + q0w + lr) * 6144 + h * HD_;
    #pragma unroll
    for (int s = 0; s < 4; ++s)
      qf[s] = *(const short8*)(qkv + qbase + s*32 + lg*8);
  }
  float m_run[4], l_run[4];
  f32x4 acc[8];
  #pragma unroll
  for (int r = 0; r < 4; ++r) { m_run[r] = -1e30f; l_run[r] = 0.f; }
  #pragma unroll
  for (int dt = 0; dt < 8; ++dt) acc[dt] = zero4();

  const int ntiles = (q0 + 64) >> 5;
  for (int jt = 0; jt < ntiles; ++jt) {
    const int j0 = jt << 5;
    // stage K tile (32 x 128) and V^T tile (128 x 32)
    #pragma unroll
    for (int c = 0; c < 2; ++c) {
      int ci = tid + 256 * c;
      int key = ci >> 4, hd8 = ci & 15;
      *(short8*)&Ks[key][hd8*8] =
        *(const short8*)(qkv + (size_t)(b*2048 + j0 + key)*6144 + 2048 + h*HD_ + hd8*8);
    }
    #pragma unroll
    for (int c = 0; c < 2; ++c) {
      int ci = tid + 256 * c;
      int hd = ci >> 2, k8 = ci & 3;
      *(short8*)&Vt[hd][k8*8] =
        *(const short8*)(vt + (size_t)(bh*HD_ + hd)*2048 + j0 + k8*8);
    }
    __syncthreads();
    // S = Q K^T  (two 16-key halves)
    f32x4 sc0 = zero4(), sc1 = zero4();
    #pragma unroll
    for (int s = 0; s < 4; ++s) {
      short8 kb0 = *(const short8*)&Ks[lr][s*32 + lg*8];
      short8 kb1 = *(const short8*)&Ks[16 + lr][s*32 + lg*8];
      sc0 = __builtin_amdgcn_mfma_f32_16x16x32_bf16(qf[s], kb0, sc0, 0, 0, 0);
      sc1 = __builtin_amdgcn_mfma_f32_16x16x32_bf16(qf[s], kb1, sc1, 0, 0, 0);
    }
    // online softmax (per row r; columns spread over lr lanes)
    float pv0[4], pv1[4], al[4];
    #pragma unroll
    for (int r = 0; r < 4; ++r) {
      const int q = q0w + lg*4 + r;
      float v0 = sc0[r] * ASCALE; if (j0 + lr > q)      v0 = -1e30f;
      float v1 = sc1[r] * ASCALE; if (j0 + 16 + lr > q) v1 = -1e30f;
      float mx = fmaxf(v0, v1);
      mx = fmaxf(mx, __shfl_xor(mx, 1, 16));
      mx = fmaxf(mx, __shfl_xor(mx, 2, 16));
      mx = fmaxf(mx, __shfl_xor(mx, 4, 16));
      mx = fmaxf(mx, __shfl_xor(mx, 8, 16));
      const float mnew = fmaxf(m_run[r], mx);
      const float a = __expf(m_run[r] - mnew);
      v0 = __expf(v0 - mnew);
      v1 = __expf(v1 - mnew);
      float rs = v0 + v1;
      rs += __shfl_xor(rs, 1, 16);
      rs += __shfl_xor(rs, 2, 16);
      rs += __shfl_xor(rs, 4, 16);
      rs += __shfl_xor(rs, 8, 16);
      l_run[r] = l_run[r] * a + rs;
      m_run[r] = mnew;
      al[r] = a; pv0[r] = v0; pv1[r] = v1;
    }
    #pragma unroll
    for (int dt = 0; dt < 8; ++dt)
      #pragma unroll
      for (int r = 0; r < 4; ++r) acc[dt][r] *= al[r];
    // P: C-layout -> LDS -> A-layout
    #pragma unroll
    for (int r = 0; r < 4; ++r) {
      Ps[w][lg*4 + r][lr]      = f2bf(pv0[r]);
      Ps[w][lg*4 + r][16 + lr] = f2bf(pv1[r]);
    }
    short8 pa = *(const short8*)&Ps[w][lr][lg*8];
    #pragma unroll
    for (int dt = 0; dt < 8; ++dt) {
      short8 vb = *(const short8*)&Vt[dt*16 + lr][lg*8];
      acc[dt] = __builtin_amdgcn_mfma_f32_16x16x32_bf16(pa, vb, acc[dt], 0, 0, 0);
    }
    __syncthreads();
  }
  #pragma unroll
  for (int dt = 0; dt < 8; ++dt) {
    #pragma unroll
    for (int r = 0; r < 4; ++r) {
      const int q = q0w + lg*4 + r;
      attnout[(size_t)(b*2048 + q)*2048 + h*HD_ + dt*16 + lr] = f2bf(acc[dt][r] / l_run[r]);
    }
  }
}

// ---------------------------------------------------------------------------
// ffn_in = silu(gate) * up   (bf16)
__global__ __launch_bounds__(256)
void silu_mul_kernel(const short* __restrict__ g, const short* __restrict__ u,
                     short* __restrict__ out)
{
  const int i = blockIdx.x * 256 + threadIdx.x;   // per short8 chunk
  short8 gv = ((const short8*)g)[i];
  short8 uv = ((const short8*)u)[i];
  short8 o;
  #pragma unroll
  for (int j = 0; j < 8; ++j) {
    float xg = bf2f(gv[j]);
    float s = xg / (1.0f + __expf(-xg));
    o[j] = f2bf(s * bf2f(uv[j]));
  }
  ((short8*)out)[i] = o;
}

// ---------------------------------------------------------------------------
extern "C" void kernel_launch(void* const* d_in, const int* in_sizes, int n_in,
                              void* d_out, int out_size, void* d_ws, size_t ws_size,
                              hipStream_t stream) {
  const float* x          = (const float*)d_in[0];
  const float* gamma      = (const float*)d_in[1];
  const float* beta       = (const float*)d_in[2];
  const float* iter_scale = (const float*)d_in[3];
  const float* qkv_bases  = (const float*)d_in[4];
  const float* o_bases    = (const float*)d_in[5];
  const float* gate_bases = (const float*)d_in[6];
  const float* up_bases   = (const float*)d_in[7];
  const float* down_bases = (const float*)d_in[8];
  const float* route_qkv  = (const float*)d_in[9];
  const float* route_o    = (const float*)d_in[10];
  const float* route_gate = (const float*)d_in[11];
  const float* route_up   = (const float*)d_in[12];
  const float* route_down = (const float*)d_in[13];
  const float* bias_qkv   = (const float*)d_in[14];
  const float* bias_o     = (const float*)d_in[15];
  const float* bias_gate  = (const float*)d_in[16];
  const float* bias_up    = (const float*)d_in[17];
  const float* bias_down  = (const float*)d_in[18];
  const float* norm1_w    = (const float*)d_in[19];
  const float* norm2_w    = (const float*)d_in[20];
  const int*   li         = (const int*)d_in[21];

  float* out0 = (float*)d_out;                  // (B,T,D) fp32
  float* aout = out0 + (size_t)BT * DD;         // a_qkv (B,T,4) fp32

  char* ws = (char*)d_ws;
  short* hbuf    = (short*)(ws + 0);            // 16.78 MB  (h / h2, bf16)
  float* alpha   = (float*)(ws + 16777216);     // 64 KB (+slack)
  short* Aexp    = (short*)(ws + 16842752);     // 67.1 MB  (BT x 8192 bf16)
  short* Bconv   = (short*)(ws + 83951616);     // 100.7 MB (bf16 bases, reused)
  short* qkvbuf  = (short*)(ws + 184614912);    // 50.3 MB  (BT x 6144 bf16)
  short* vtbuf   = (short*)(ws + 234946560);    // 16.78 MB
  short* attnout = (short*)(ws + 251723776);    // 16.78 MB ; total 268.5 MB
  // aliases (lifetimes are disjoint):
  float* x_attn  = (float*)(ws + 184614912);    // 33.55 MB over dead qkvbuf
  short* gatebuf = (short*)(ws + 234946560);    // over dead vtbuf
  short* upbuf   = (short*)(ws + 251723776);    // over dead attnout

  const int NCH_QKV = 50331648 / 8;   // qkv_bases chunks
  const int NCH_D   = 16777216 / 8;   // o/gate/up/down bases chunks

  // h = rmsnorm(x, norm1_w)*gamma + beta
  rmsnorm_kernel<<<BT, 256, 0, stream>>>(x, norm1_w, gamma, beta, hbuf);
  // qkv mixed linear (also emits a_qkv output)
  cvt_bf16_kernel<<<NCH_QKV/256, 256, 0, stream>>>(qkv_bases, Bconv, NCH_QKV);
  route_kernel<<<BT, 64, 0, stream>>>(hbuf, route_qkv, bias_qkv, li, alpha, aout);
  expand_kernel<<<BT, 256, 0, stream>>>(hbuf, alpha, Aexp);
  gemm_mixed<<<dim3(48, 32), 256, 0, stream>>>(Aexp, Bconv, 6144, 0,
                                               nullptr, nullptr, nullptr, qkvbuf);
  // attention
  transpose_v_kernel<<<dim3(32, 2, 32), 256, 0, stream>>>(qkvbuf, vtbuf);
  attn_kernel<<<1024, 256, 0, stream>>>(qkvbuf, vtbuf, attnout);
  // o mixed linear + residual -> x_attn (fp32)
  cvt_bf16_kernel<<<NCH_D/256, 256, 0, stream>>>(o_bases, Bconv, NCH_D);
  route_kernel<<<BT, 64, 0, stream>>>(attnout, route_o, bias_o, li, alpha, nullptr);
  expand_kernel<<<BT, 256, 0, stream>>>(attnout, alpha, Aexp);
  gemm_mixed<<<dim3(16, 32), 256, 0, stream>>>(Aexp, Bconv, 2048, 2,
                                               x, nullptr, nullptr, x_attn);
  // h2 = rmsnorm(x_attn, norm2_w)*gamma + beta
  rmsnorm_kernel<<<BT, 256, 0, stream>>>(x_attn, norm2_w, gamma, beta, hbuf);
  // gate
  cvt_bf16_kernel<<<NCH_D/256, 256, 0, stream>>>(gate_bases, Bconv, NCH_D);
  route_kernel<<<BT, 64, 0, stream>>>(hbuf, route_gate, bias_gate, li, alpha, nullptr);
  expand_kernel<<<BT, 256, 0, stream>>>(hbuf, alpha, Aexp);
  gemm_mixed<<<dim3(16, 32), 256, 0, stream>>>(Aexp, Bconv, 2048, 0,
                                               nullptr, nullptr, nullptr, gatebuf);
  // up
  cvt_bf16_kernel<<<NCH_D/256, 256, 0, stream>>>(up_bases, Bconv, NCH_D);
  route_kernel<<<BT, 64, 0, stream>>>(hbuf, route_up, bias_up, li, alpha, nullptr);
  expand_kernel<<<BT, 256, 0, stream>>>(hbuf, alpha, Aexp);
  gemm_mixed<<<dim3(16, 32), 256, 0, stream>>>(Aexp, Bconv, 2048, 0,
                                               nullptr, nullptr, nullptr, upbuf);
  // ffn_in = silu(gate)*up
  silu_mul_kernel<<<4096, 256, 0, stream>>>(gatebuf, upbuf, gatebuf);
  // down mixed linear + final residual/iter_scale -> out0
  cvt_bf16_kernel<<<NCH_D/256, 256, 0, stream>>>(down_bases, Bconv, NCH_D);
  route_kernel<<<BT, 64, 0, stream>>>(gatebuf, route_down, bias_down, li, alpha, nullptr);
  expand_kernel<<<BT, 256, 0, stream>>>(gatebuf, alpha, Aexp);
  gemm_mixed<<<dim3(16, 32), 256, 0, stream>>>(Aexp, Bconv, 2048, 3,
                                               x, x_attn, iter_scale, out0);
}